// Round 3
// baseline (225.631 us; speedup 1.0000x reference)
//
#include <hip/hip_runtime.h>
#include <hip/hip_bf16.h>

// OneStep: out = W - c * K^T (K W - V),  c = 0.2/(CTX*D) = 9.5367431640625e-8
// W:(4096,4096) K:(512,4096) V:(512,4096) fp32 -> out (4096,4096) fp32.
// bf16 MFMA w/ fp32 acc => absmax 2.441e-4 = 1 bf16 ulp (threshold 1.69e-3).
//
// R8 post-mortem: k2 dropped out of top-5 (<46us); k1 now the bottleneck at
// 46us, MfmaUtil 13.7%, HBM 13%, Occ 16% (LDS 64KB -> 2 blocks/CU).
// Latency-bound: 16 MFMA (~80cyc) per K-tile vs ~300cyc gld->LDS->ds_read
// chain at depth-1 prefetch.
// R9: k1 goes REGISTER-DIRECT -- MFMA fragments loaded straight from Wt/Kb
// to VGPRs (the fragment pattern is already 64B-coalesced: 4 quads cover 16
// rows x 64B contiguous). No LDS staging, no barriers, 3-deep register
// pipeline (16-24 loads in flight, compiler emits exact counted vmcnt).
// LDS shrinks to the 17.4KB cross-wave reduce buffer.

typedef __bf16 bf16_t;
typedef __bf16 bf16x8 __attribute__((ext_vector_type(8)));
typedef float f32x4 __attribute__((ext_vector_type(4)));

#define D_DIM 4096
#define CTX_N 512
#define UPD_SCALE 9.5367431640625e-8f

__device__ __forceinline__ void gld16(const bf16_t* g, bf16_t* l) {
    __builtin_amdgcn_global_load_lds(
        (const __attribute__((address_space(1))) void*)g,
        (__attribute__((address_space(3))) void*)l, 16, 0, 0);
}

// ---- transpose+convert: src (M x N) fp32 tile -> dstT (N x M) bf16
//      [+ dstN (M x N) bf16].  64x64 tile at (bx,by); pad-65 (2-way = free).
__device__ __forceinline__ void t_body2(
    float* tile, const float* __restrict__ src, bf16_t* __restrict__ dstT,
    bf16_t* __restrict__ dstN, int M, int N, int bx, int by)
{
    const int tid = threadIdx.x;
    const int C0 = bx * 64, R0 = by * 64;
    const int r  = tid >> 2, cs = (tid & 3) * 16;

    const float* s = src + (size_t)(R0 + r) * N + C0 + cs;
    float f[16];
#pragma unroll
    for (int u = 0; u < 4; ++u) {
        const float4 v = ((const float4*)s)[u];
        f[4 * u + 0] = v.x; f[4 * u + 1] = v.y; f[4 * u + 2] = v.z; f[4 * u + 3] = v.w;
    }
#pragma unroll
    for (int u = 0; u < 16; ++u) tile[r * 65 + cs + u] = f[u];

    if (dstN) {
        bf16x8 v0, v1;
#pragma unroll
        for (int u = 0; u < 8; ++u) { v0[u] = (bf16_t)f[u]; v1[u] = (bf16_t)f[8 + u]; }
        bf16_t* d = dstN + (size_t)(R0 + r) * N + C0 + cs;
        *(bf16x8*)d = v0; *(bf16x8*)(d + 8) = v1;
    }
    __syncthreads();

    bf16x8 o0, o1;
#pragma unroll
    for (int u = 0; u < 8; ++u) {
        o0[u] = (bf16_t)tile[(cs + u) * 65 + r];
        o1[u] = (bf16_t)tile[(cs + 8 + u) * 65 + r];
    }
    bf16_t* d = dstT + (size_t)(C0 + r) * M + R0 + cs;
    *(bf16x8*)d = o0; *(bf16x8*)(d + 8) = o1;
}

// One launch for all three transposes: y<64 -> W, 64..71 -> K(+Kb), 72..79 -> V
__global__ __launch_bounds__(256) void t_all(
    const float* __restrict__ W, const float* __restrict__ K,
    const float* __restrict__ V, bf16_t* __restrict__ Wt,
    bf16_t* __restrict__ Kt, bf16_t* __restrict__ Kb, bf16_t* __restrict__ Vt)
{
    __shared__ float tile[64 * 65];
    const int y = blockIdx.y;
    if (y < 64)      t_body2(tile, W, Wt, nullptr, D_DIM, D_DIM, blockIdx.x, y);
    else if (y < 72) t_body2(tile, K, Kt, Kb,      CTX_N, D_DIM, blockIdx.x, y - 64);
    else             t_body2(tile, V, Vt, nullptr, CTX_N, D_DIM, blockIdx.x, y - 72);
}

// MFMA 16x16x32 bf16 (m89/m91): A/B frag: row=lane&15, k=quad*8+j (8 bf16);
// C/D: col=lane&15, row=quad*4+reg.  D[m][n] = sum_k A(m,k)*B(n,k).

// ---- K1: Rt[j][c] = sum_k Wt[j][k]*Kb[c][k] - Vt[j][c]  (4096 x 512) ----
// Barrier-free K-split: wave w owns k in [w*1024, w*1024+1024), 64x64 tile.
// REGISTER-DIRECT: fragments loaded straight from global (no LDS staging).
// Per fixed frag the wave's 64 lanes cover 16 rows x 64B contiguous -> fully
// coalesced. 3-deep register pipeline; compiler emits counted vmcnt waits.
// grid (64 j, 8 c): id%8 = j%8 pins the 8 c-sharers of a Wt slice to one XCD.

#define K1_LOAD(AR, BR, T)                                                   \
    _Pragma("unroll")                                                        \
    for (int x = 0; x < 4; ++x) {                                            \
        AR[x] = *(const bf16x8*)(pA + (size_t)(x * 16) * D_DIM + (T) * 32);  \
        BR[x] = *(const bf16x8*)(pB + (size_t)(x * 16) * D_DIM + (T) * 32);  \
    }

#define K1_MFMA(AR, BR)                                                      \
    _Pragma("unroll")                                                        \
    for (int mi = 0; mi < 4; ++mi)                                           \
        _Pragma("unroll")                                                    \
        for (int ni = 0; ni < 4; ++ni)                                       \
            acc[mi][ni] = __builtin_amdgcn_mfma_f32_16x16x32_bf16(           \
                AR[mi], BR[ni], acc[mi][ni], 0, 0, 0);

__global__ __launch_bounds__(256) void k1_residual(
    const bf16_t* __restrict__ Wt, const bf16_t* __restrict__ Kb,
    const bf16_t* __restrict__ Vt, bf16_t* __restrict__ Rt)
{
    __shared__ __align__(16) float ep[64 * 68];  // 17.4 KB reduce buffer

    const int tid = threadIdx.x, wave = tid >> 6, lane = tid & 63;
    const int j0 = blockIdx.x * 64, c0 = blockIdx.y * 64;
    const int l15 = lane & 15, quad = lane >> 4;
    const int kw = wave * 1024;

    f32x4 acc[4][4] = {};

    // lane's base addr: row (j0/c0 + l15), col kw + quad*8; frag x at +x*16
    // rows; tile T at +T*32 cols.
    const bf16_t* pA = Wt + (size_t)(j0 + l15) * D_DIM + kw + quad * 8;
    const bf16_t* pB = Kb + (size_t)(c0 + l15) * D_DIM + kw + quad * 8;

    bf16x8 a0[4], b0[4], a1[4], b1[4], a2[4], b2[4];

    // 32 K-tiles of 32. Prologue: tiles 0..2 in flight (24 loads).
    K1_LOAD(a0, b0, 0);
    K1_LOAD(a1, b1, 1);
    K1_LOAD(a2, b2, 2);
#pragma unroll 1
    for (int t = 0; t < 27; t += 3) {
        K1_MFMA(a0, b0); K1_LOAD(a0, b0, t + 3);
        K1_MFMA(a1, b1); K1_LOAD(a1, b1, t + 4);
        K1_MFMA(a2, b2); K1_LOAD(a2, b2, t + 5);
    }
    // tiles 27..31 (loads 30,31 issued under compute of 27,28)
    K1_MFMA(a0, b0); K1_LOAD(a0, b0, 30);
    K1_MFMA(a1, b1); K1_LOAD(a1, b1, 31);
    K1_MFMA(a2, b2);
    K1_MFMA(a0, b0);
    K1_MFMA(a1, b1);

    // Cross-wave reduction through ep[64][68].
    __syncthreads();
#pragma unroll
    for (int w = 0; w < 4; ++w) {
        if (wave == w) {
#pragma unroll
            for (int mi = 0; mi < 4; ++mi)
#pragma unroll
                for (int ni = 0; ni < 4; ++ni)
#pragma unroll
                    for (int r = 0; r < 4; ++r) {
                        const int row = mi * 16 + quad * 4 + r;
                        const int col = ni * 16 + l15;
                        if (w == 0) ep[row * 68 + col]  = acc[mi][ni][r];
                        else        ep[row * 68 + col] += acc[mi][ni][r];
                    }
        }
        __syncthreads();
    }

    // Epilogue: Rt = ep - Vt, vectorized.
    {
        const int row = tid >> 2, cs = (tid & 3) * 16;
        const size_t rbase = (size_t)(j0 + row) * CTX_N + c0 + cs;
        float e[16];
#pragma unroll
        for (int u = 0; u < 4; ++u) {
            const float4 v = ((const float4*)(ep + row * 68 + cs))[u];
            e[4 * u + 0] = v.x; e[4 * u + 1] = v.y;
            e[4 * u + 2] = v.z; e[4 * u + 3] = v.w;
        }
        const bf16x8 v0 = *(const bf16x8*)(Vt + rbase);
        const bf16x8 v1 = *(const bf16x8*)(Vt + rbase + 8);
        bf16x8 o0, o1;
#pragma unroll
        for (int u = 0; u < 8; ++u) {
            o0[u] = (bf16_t)(e[u]     - (float)v0[u]);
            o1[u] = (bf16_t)(e[8 + u] - (float)v1[u]);
        }
        *(bf16x8*)(Rt + rbase)     = o0;
        *(bf16x8*)(Rt + rbase + 8) = o1;
    }
}

// ---- K2: out[i][j] = W[i][j] - c * sum_c Kt[i][c]*Rt[j][c]  (4096x4096) ----
// 128x128 tile, BK=32, 4 waves of 64x64. Double-buffered staging (2x16 KB):
// stage(t+1) issued before compute(t), one __syncthreads per K-step.
// Epilogue is BARRIER-FREE: direct per-fragment W load (prefetched one
// mi-block ahead, statically indexed), FMA, dword store. Bijective XCD
// swizzle: 32 blocks sharing a Kt i-slice -> one XCD.

#define K2_COMPUTE(BSEL)                                                     \
    {                                                                        \
        const bf16_t* As = (const bf16_t*)(smem + (BSEL) * 16384);           \
        const bf16_t* Bs = (const bf16_t*)(smem + (BSEL) * 16384 + 8192);    \
        bf16x8 af[4], bq[4];                                                 \
        _Pragma("unroll")                                                    \
        for (int mi = 0; mi < 4; ++mi)                                       \
            af[mi] = *(const bf16x8*)(As + (wi + mi * 16 + l15) * 32 + quad * 8); \
        _Pragma("unroll")                                                    \
        for (int ni = 0; ni < 4; ++ni)                                       \
            bq[ni] = *(const bf16x8*)(Bs + (wj + ni * 16 + l15) * 32 + quad * 8); \
        _Pragma("unroll")                                                    \
        for (int mi = 0; mi < 4; ++mi)                                       \
            _Pragma("unroll")                                                \
            for (int ni = 0; ni < 4; ++ni)                                   \
                acc[mi][ni] = __builtin_amdgcn_mfma_f32_16x16x32_bf16(       \
                    af[mi], bq[ni], acc[mi][ni], 0, 0, 0);                   \
    }

__global__ __launch_bounds__(256) void k2_update(
    const bf16_t* __restrict__ Kt, const bf16_t* __restrict__ Rt,
    const float* __restrict__ W, float* __restrict__ out)
{
    __shared__ __align__(16) char smem[32768];  // buf0 16KB | buf1 16KB

    const int tid = threadIdx.x;

    // Bijective XCD swizzle: id = 8*xp + (yp&7) + 256*(yp>>3).
    // Same yp (same Kt i-slice) -> same id%8 -> same XCD L2.
    const int id = blockIdx.x + 32 * blockIdx.y;
    const int xp = (id >> 3) & 31;
    const int yp = (id & 7) + 8 * (id >> 8);
    const int j0 = xp * 128, i0 = yp * 128;

    const int lane = tid & 63, wave = tid >> 6;
    const int wi = (wave >> 1) * 64, wj = (wave & 1) * 64;
    const int l15 = lane & 15, quad = lane >> 4;

    f32x4 acc[4][4] = {};

    const bf16_t* ga = Kt + (size_t)(i0 + (tid >> 2)) * CTX_N + (tid & 3) * 8;
    const bf16_t* gb = Rt + (size_t)(j0 + (tid >> 2)) * CTX_N + (tid & 3) * 8;

    auto stage = [&](int bsel, int cc) {
        bf16_t* la = (bf16_t*)(smem + bsel * 16384) + tid * 8;
        bf16_t* lb = (bf16_t*)(smem + bsel * 16384 + 8192) + tid * 8;
        gld16(ga + cc, la);
        gld16(ga + cc + (size_t)64 * CTX_N, la + 64 * 32);
        gld16(gb + cc, lb);
        gld16(gb + cc + (size_t)64 * CTX_N, lb + 64 * 32);
    };

    // 16 K-tiles of 32. Prologue: tile 0 -> buf0.
    stage(0, 0);
    __syncthreads();
#pragma unroll 1
    for (int t = 1; t <= 13; t += 2) {
        stage(1, t * 32);
        __builtin_amdgcn_sched_barrier(0);
        K2_COMPUTE(0);                  // tile t-1
        __syncthreads();
        stage(0, (t + 1) * 32);
        __builtin_amdgcn_sched_barrier(0);
        K2_COMPUTE(1);                  // tile t
        __syncthreads();
    }
    stage(1, 15 * 32);
    __builtin_amdgcn_sched_barrier(0);
    K2_COMPUTE(0);                      // tile 14
    __syncthreads();
    K2_COMPUTE(1);                      // tile 15

    // ---- Barrier-free direct epilogue ----
    // acc[mi][ni][r] maps to row = i0+wi+mi*16+quad*4+r, col = j0+wj+ni*16+l15.
    const size_t base = (size_t)(i0 + wi + quad * 4) * D_DIM + j0 + wj + l15;
    const float* wp = W + base;
    float*       op = out + base;

    // Prefetch mi=0's 16 W fragments.
    float w0[16], w1[16];
#pragma unroll
    for (int r = 0; r < 4; ++r)
#pragma unroll
        for (int ni = 0; ni < 4; ++ni)
            w0[r * 4 + ni] = wp[(size_t)r * D_DIM + ni * 16];

#pragma unroll
    for (int mi = 0; mi < 4; ++mi) {
        float* wcur = (mi & 1) ? w1 : w0;
        float* wnxt = (mi & 1) ? w0 : w1;
        if (mi < 3) {
#pragma unroll
            for (int r = 0; r < 4; ++r)
#pragma unroll
                for (int ni = 0; ni < 4; ++ni)
                    wnxt[r * 4 + ni] =
                        wp[(size_t)((mi + 1) * 16 + r) * D_DIM + ni * 16];
        }
#pragma unroll
        for (int r = 0; r < 4; ++r)
#pragma unroll
            for (int ni = 0; ni < 4; ++ni)
                op[(size_t)(mi * 16 + r) * D_DIM + ni * 16] =
                    wcur[r * 4 + ni] - UPD_SCALE * acc[mi][ni][r];
    }
}

extern "C" void kernel_launch(void* const* d_in, const int* in_sizes, int n_in,
                              void* d_out, int out_size, void* d_ws, size_t ws_size,
                              hipStream_t stream) {
    const float* W = (const float*)d_in[0];   // (4096, 4096)
    const float* K = (const float*)d_in[1];   // (512, 4096)
    const float* V = (const float*)d_in[2];   // (512, 4096)
    float* out = (float*)d_out;

    char* ws = (char*)d_ws;                    // 48 MB used
    bf16_t* Wt = (bf16_t*)(ws);                            // (4096,4096) W^T
    bf16_t* Kt = (bf16_t*)(ws + (size_t)32 * 1024 * 1024); // (4096,512) K^T
    bf16_t* Kb = (bf16_t*)(ws + (size_t)36 * 1024 * 1024); // (512,4096) K
    bf16_t* Vt = (bf16_t*)(ws + (size_t)40 * 1024 * 1024); // (4096,512) V^T
    bf16_t* Rt = (bf16_t*)(ws + (size_t)44 * 1024 * 1024); // (4096,512) R^T

    t_all      <<<dim3(64, 80), 256, 0, stream>>>(W, K, V, Wt, Kt, Kb, Vt);
    k1_residual<<<dim3(64, 8),  256, 0, stream>>>(Wt, Kb, Vt, Rt);
    k2_update  <<<dim3(32, 32), 256, 0, stream>>>(Kt, Rt, W, out);
}

// Round 4
// 217.115 us; speedup vs baseline: 1.0392x; 1.0392x over previous
//
#include <hip/hip_runtime.h>
#include <hip/hip_bf16.h>

// OneStep: out = W - c * K^T (K W - V),  c = 0.2/(CTX*D) = 9.5367431640625e-8
// W:(4096,4096) K:(512,4096) V:(512,4096) fp32 -> out (4096,4096) fp32.
// bf16 MFMA w/ fp32 acc => absmax 2.441e-4 = 1 bf16 ulp (threshold 1.69e-3).
//
// R9 post-mortem: register-direct k1 REGRESSED (46->67us): VGPR cap (116)
// broke the 3-deep pipeline. Re-derivation: R7-k1 moved 537 MB of L2 traffic
// at 11.7 TB/s = ~19 B/cyc/CU -- the SAME streaming rate m97/8-phase GEMMs
// sustain. k1 is TRAFFIC-bound at the empirical per-CU ceiling, not latency.
// R10: cut traffic 25%: BM=128 x BN=64 tile (403 MB), grid 32x8 = 1 block/CU,
// wave-private K-split (K=1024/wave), dbuf + counted vmcnt(12) (never 0
// in-loop). Frag-ordered staging: gld16 lane map == fragment read order ->
// LDS frag reads are lane-linear 16B, conflict-free (kills the 2^21
// SQ_LDS_BANK_CONFLICT; global footprint unchanged: 16 rows x 64B/instr).
// launch_bounds(256,1): ~200 VGPR needed (acc[8][4]+frags), 1 block/CU by grid.

typedef __bf16 bf16_t;
typedef __bf16 bf16x8 __attribute__((ext_vector_type(8)));
typedef float f32x4 __attribute__((ext_vector_type(4)));

#define D_DIM 4096
#define CTX_N 512
#define UPD_SCALE 9.5367431640625e-8f

__device__ __forceinline__ void gld16(const bf16_t* g, bf16_t* l) {
    __builtin_amdgcn_global_load_lds(
        (const __attribute__((address_space(1))) void*)g,
        (__attribute__((address_space(3))) void*)l, 16, 0, 0);
}

// ---- transpose+convert: src (M x N) fp32 tile -> dstT (N x M) bf16
//      [+ dstN (M x N) bf16].  64x64 tile at (bx,by); pad-65 (2-way = free).
__device__ __forceinline__ void t_body2(
    float* tile, const float* __restrict__ src, bf16_t* __restrict__ dstT,
    bf16_t* __restrict__ dstN, int M, int N, int bx, int by)
{
    const int tid = threadIdx.x;
    const int C0 = bx * 64, R0 = by * 64;
    const int r  = tid >> 2, cs = (tid & 3) * 16;

    const float* s = src + (size_t)(R0 + r) * N + C0 + cs;
    float f[16];
#pragma unroll
    for (int u = 0; u < 4; ++u) {
        const float4 v = ((const float4*)s)[u];
        f[4 * u + 0] = v.x; f[4 * u + 1] = v.y; f[4 * u + 2] = v.z; f[4 * u + 3] = v.w;
    }
#pragma unroll
    for (int u = 0; u < 16; ++u) tile[r * 65 + cs + u] = f[u];

    if (dstN) {
        bf16x8 v0, v1;
#pragma unroll
        for (int u = 0; u < 8; ++u) { v0[u] = (bf16_t)f[u]; v1[u] = (bf16_t)f[8 + u]; }
        bf16_t* d = dstN + (size_t)(R0 + r) * N + C0 + cs;
        *(bf16x8*)d = v0; *(bf16x8*)(d + 8) = v1;
    }
    __syncthreads();

    bf16x8 o0, o1;
#pragma unroll
    for (int u = 0; u < 8; ++u) {
        o0[u] = (bf16_t)tile[(cs + u) * 65 + r];
        o1[u] = (bf16_t)tile[(cs + 8 + u) * 65 + r];
    }
    bf16_t* d = dstT + (size_t)(C0 + r) * M + R0 + cs;
    *(bf16x8*)d = o0; *(bf16x8*)(d + 8) = o1;
}

// One launch for all three transposes: y<64 -> W, 64..71 -> K(+Kb), 72..79 -> V
__global__ __launch_bounds__(256) void t_all(
    const float* __restrict__ W, const float* __restrict__ K,
    const float* __restrict__ V, bf16_t* __restrict__ Wt,
    bf16_t* __restrict__ Kt, bf16_t* __restrict__ Kb, bf16_t* __restrict__ Vt)
{
    __shared__ float tile[64 * 65];
    const int y = blockIdx.y;
    if (y < 64)      t_body2(tile, W, Wt, nullptr, D_DIM, D_DIM, blockIdx.x, y);
    else if (y < 72) t_body2(tile, K, Kt, Kb,      CTX_N, D_DIM, blockIdx.x, y - 64);
    else             t_body2(tile, V, Vt, nullptr, CTX_N, D_DIM, blockIdx.x, y - 72);
}

// MFMA 16x16x32 bf16 (m89/m91): A/B frag: row=lane&15, k=quad*8+j (8 bf16);
// C/D: col=lane&15, row=quad*4+reg.  D[m][n] = sum_k A(m,k)*B(n,k).

// ---- K1: Rt[j][c] = sum_k Wt[j][k]*Kb[c][k] - Vt[j][c]  (4096 x 512) ----
// 128(j) x 64(c) tile, grid (32,8) = 256 blocks = 1/CU. Barrier-free
// wave-private K-split: wave w owns k in [w*1024, w*1024+1024).
// Per wave per K-step(32): A 8 frag-blocks (8KB) + B 4 (4KB), double-
// buffered (24KB/wave, 96KB/block). Frag-ordered staging: gld16 #f's lane l
// loads row (f*16 + (l&15)), col seg (l>>4)*8 -> LDS slot lane*16B; frag
// read = lane-linear 16B at f*1024, conflict-free.
// Steady state: issue A(t+1) -> vmcnt(12) -> read A(t) -> issue B(t+1)
// -> vmcnt(12) -> read B(t) -> 32 MFMA. vmcnt hits 0 only at the tail.

__global__ __launch_bounds__(256, 1) void k1_residual(
    const bf16_t* __restrict__ Wt, const bf16_t* __restrict__ Kb,
    const bf16_t* __restrict__ Vt, bf16_t* __restrict__ Rt)
{
    __shared__ __align__(16) char smem[98304];  // 4 waves x 2 x (A 8K + B 4K)

    const int tid = threadIdx.x, wave = tid >> 6, lane = tid & 63;
    const int j0 = blockIdx.x * 128, c0 = blockIdx.y * 64;
    const int l15 = lane & 15, quad = lane >> 4;
    const int kw = wave * 1024;

    bf16_t* reg = (bf16_t*)(smem + wave * 24576);  // per-wave staging (elems)

    f32x4 acc[8][4] = {};

    // Per-lane global base: row (+l15), col seg (+quad*8); frag f adds
    // f*16 rows; tile t adds t*32 cols.
    const bf16_t* ga = Wt + (size_t)(j0 + l15) * D_DIM + kw + quad * 8;
    const bf16_t* gb = Kb + (size_t)(c0 + l15) * D_DIM + kw + quad * 8;

    auto stageA = [&](int off, int t) {
        bf16_t* d = reg + off + lane * 8;
#pragma unroll
        for (int mi = 0; mi < 8; ++mi)
            gld16(ga + (size_t)(mi * 16) * D_DIM + t * 32, d + mi * 512);
    };
    auto stageB = [&](int off, int t) {
        bf16_t* d = reg + off + 4096 + lane * 8;
#pragma unroll
        for (int ni = 0; ni < 4; ++ni)
            gld16(gb + (size_t)(ni * 16) * D_DIM + t * 32, d + ni * 512);
    };

    // 32 K-tiles of 32. Prologue: tile 0 -> buf0 (12 loads outstanding).
    stageA(0, 0); stageB(0, 0);
#pragma unroll 1
    for (int t = 0; t < 31; ++t) {
        const int cur = (t & 1) ? 6144 : 0;   // elems: buf = 6144 (12KB)
        const int nxt = 6144 - cur;

        stageA(nxt, t + 1);
        __builtin_amdgcn_sched_barrier(0);
        __builtin_amdgcn_s_waitcnt(0x0f7c);   // vmcnt(12): A(t) done
        __builtin_amdgcn_sched_barrier(0);
        bf16x8 a[8];
#pragma unroll
        for (int mi = 0; mi < 8; ++mi)
            a[mi] = *(const bf16x8*)(reg + cur + mi * 512 + lane * 8);

        stageB(nxt, t + 1);
        __builtin_amdgcn_sched_barrier(0);
        __builtin_amdgcn_s_waitcnt(0x0f7c);   // vmcnt(12): B(t) done
        __builtin_amdgcn_sched_barrier(0);
        bf16x8 b[4];
#pragma unroll
        for (int ni = 0; ni < 4; ++ni)
            b[ni] = *(const bf16x8*)(reg + cur + 4096 + ni * 512 + lane * 8);

#pragma unroll
        for (int mi = 0; mi < 8; ++mi)
#pragma unroll
            for (int ni = 0; ni < 4; ++ni)
                acc[mi][ni] = __builtin_amdgcn_mfma_f32_16x16x32_bf16(
                    a[mi], b[ni], acc[mi][ni], 0, 0, 0);
    }
    {   // tile 31 (in buf 6144); drain to 0 only here.
        __builtin_amdgcn_s_waitcnt(0x0f74);   // vmcnt(4): A(31) done
        __builtin_amdgcn_sched_barrier(0);
        bf16x8 a[8];
#pragma unroll
        for (int mi = 0; mi < 8; ++mi)
            a[mi] = *(const bf16x8*)(reg + 6144 + mi * 512 + lane * 8);
        __builtin_amdgcn_s_waitcnt(0x0f70);   // vmcnt(0): B(31) done
        __builtin_amdgcn_sched_barrier(0);
        bf16x8 b[4];
#pragma unroll
        for (int ni = 0; ni < 4; ++ni)
            b[ni] = *(const bf16x8*)(reg + 6144 + 4096 + ni * 512 + lane * 8);
#pragma unroll
        for (int mi = 0; mi < 8; ++mi)
#pragma unroll
            for (int ni = 0; ni < 4; ++ni)
                acc[mi][ni] = __builtin_amdgcn_mfma_f32_16x16x32_bf16(
                    a[mi], b[ni], acc[mi][ni], 0, 0, 0);
    }

    // Cross-wave reduction: ep[128][68] f32 (34.8 KB) aliases dead staging.
    float* ep = (float*)smem;
    __syncthreads();
#pragma unroll
    for (int w = 0; w < 4; ++w) {
        if (wave == w) {
#pragma unroll
            for (int mi = 0; mi < 8; ++mi)
#pragma unroll
                for (int ni = 0; ni < 4; ++ni)
#pragma unroll
                    for (int r = 0; r < 4; ++r) {
                        const int row = mi * 16 + quad * 4 + r;
                        const int col = ni * 16 + l15;
                        if (w == 0) ep[row * 68 + col]  = acc[mi][ni][r];
                        else        ep[row * 68 + col] += acc[mi][ni][r];
                    }
        }
        __syncthreads();
    }

    // Epilogue: Rt = ep - Vt. 2 threads/row x 128 rows, 32 cols each.
    {
        const int row = tid >> 1, cs = (tid & 1) * 32;
        const size_t rbase = (size_t)(j0 + row) * CTX_N + c0 + cs;
        const float* erow = ep + row * 68 + cs;
#pragma unroll
        for (int u = 0; u < 4; ++u) {
            const bf16x8 vv = *(const bf16x8*)(Vt + rbase + u * 8);
            bf16x8 o;
#pragma unroll
            for (int j = 0; j < 8; ++j)
                o[j] = (bf16_t)(erow[u * 8 + j] - (float)vv[j]);
            *(bf16x8*)(Rt + rbase + u * 8) = o;
        }
    }
}

// ---- K2: out[i][j] = W[i][j] - c * sum_c Kt[i][c]*Rt[j][c]  (4096x4096) ----
// 128x128 tile, BK=32, 4 waves of 64x64. Double-buffered staging (2x16 KB):
// stage(t+1) issued before compute(t), one __syncthreads per K-step.
// Epilogue is BARRIER-FREE: direct per-fragment W load (prefetched one
// mi-block ahead, statically indexed), FMA, dword store. Bijective XCD
// swizzle: 32 blocks sharing a Kt i-slice -> one XCD.

#define K2_COMPUTE(BSEL)                                                     \
    {                                                                        \
        const bf16_t* As = (const bf16_t*)(smem + (BSEL) * 16384);           \
        const bf16_t* Bs = (const bf16_t*)(smem + (BSEL) * 16384 + 8192);    \
        bf16x8 af[4], bq[4];                                                 \
        _Pragma("unroll")                                                    \
        for (int mi = 0; mi < 4; ++mi)                                       \
            af[mi] = *(const bf16x8*)(As + (wi + mi * 16 + l15) * 32 + quad * 8); \
        _Pragma("unroll")                                                    \
        for (int ni = 0; ni < 4; ++ni)                                       \
            bq[ni] = *(const bf16x8*)(Bs + (wj + ni * 16 + l15) * 32 + quad * 8); \
        _Pragma("unroll")                                                    \
        for (int mi = 0; mi < 4; ++mi)                                       \
            _Pragma("unroll")                                                \
            for (int ni = 0; ni < 4; ++ni)                                   \
                acc[mi][ni] = __builtin_amdgcn_mfma_f32_16x16x32_bf16(       \
                    af[mi], bq[ni], acc[mi][ni], 0, 0, 0);                   \
    }

__global__ __launch_bounds__(256) void k2_update(
    const bf16_t* __restrict__ Kt, const bf16_t* __restrict__ Rt,
    const float* __restrict__ W, float* __restrict__ out)
{
    __shared__ __align__(16) char smem[32768];  // buf0 16KB | buf1 16KB

    const int tid = threadIdx.x;

    // Bijective XCD swizzle: id = 8*xp + (yp&7) + 256*(yp>>3).
    // Same yp (same Kt i-slice) -> same id%8 -> same XCD L2.
    const int id = blockIdx.x + 32 * blockIdx.y;
    const int xp = (id >> 3) & 31;
    const int yp = (id & 7) + 8 * (id >> 8);
    const int j0 = xp * 128, i0 = yp * 128;

    const int lane = tid & 63, wave = tid >> 6;
    const int wi = (wave >> 1) * 64, wj = (wave & 1) * 64;
    const int l15 = lane & 15, quad = lane >> 4;

    f32x4 acc[4][4] = {};

    const bf16_t* ga = Kt + (size_t)(i0 + (tid >> 2)) * CTX_N + (tid & 3) * 8;
    const bf16_t* gb = Rt + (size_t)(j0 + (tid >> 2)) * CTX_N + (tid & 3) * 8;

    auto stage = [&](int bsel, int cc) {
        bf16_t* la = (bf16_t*)(smem + bsel * 16384) + tid * 8;
        bf16_t* lb = (bf16_t*)(smem + bsel * 16384 + 8192) + tid * 8;
        gld16(ga + cc, la);
        gld16(ga + cc + (size_t)64 * CTX_N, la + 64 * 32);
        gld16(gb + cc, lb);
        gld16(gb + cc + (size_t)64 * CTX_N, lb + 64 * 32);
    };

    // 16 K-tiles of 32. Prologue: tile 0 -> buf0.
    stage(0, 0);
    __syncthreads();
#pragma unroll 1
    for (int t = 1; t <= 13; t += 2) {
        stage(1, t * 32);
        __builtin_amdgcn_sched_barrier(0);
        K2_COMPUTE(0);                  // tile t-1
        __syncthreads();
        stage(0, (t + 1) * 32);
        __builtin_amdgcn_sched_barrier(0);
        K2_COMPUTE(1);                  // tile t
        __syncthreads();
    }
    stage(1, 15 * 32);
    __builtin_amdgcn_sched_barrier(0);
    K2_COMPUTE(0);                      // tile 14
    __syncthreads();
    K2_COMPUTE(1);                      // tile 15

    // ---- Barrier-free direct epilogue ----
    // acc[mi][ni][r] maps to row = i0+wi+mi*16+quad*4+r, col = j0+wj+ni*16+l15.
    const size_t base = (size_t)(i0 + wi + quad * 4) * D_DIM + j0 + wj + l15;
    const float* wp = W + base;
    float*       op = out + base;

    // Prefetch mi=0's 16 W fragments.
    float w0[16], w1[16];
#pragma unroll
    for (int r = 0; r < 4; ++r)
#pragma unroll
        for (int ni = 0; ni < 4; ++ni)
            w0[r * 4 + ni] = wp[(size_t)r * D_DIM + ni * 16];

#pragma unroll
    for (int mi = 0; mi < 4; ++mi) {
        float* wcur = (mi & 1) ? w1 : w0;
        float* wnxt = (mi & 1) ? w0 : w1;
        if (mi < 3) {
#pragma unroll
            for (int r = 0; r < 4; ++r)
#pragma unroll
                for (int ni = 0; ni < 4; ++ni)
                    wnxt[r * 4 + ni] =
                        wp[(size_t)((mi + 1) * 16 + r) * D_DIM + ni * 16];
        }
#pragma unroll
        for (int r = 0; r < 4; ++r)
#pragma unroll
            for (int ni = 0; ni < 4; ++ni)
                op[(size_t)(mi * 16 + r) * D_DIM + ni * 16] =
                    wcur[r * 4 + ni] - UPD_SCALE * acc[mi][ni][r];
    }
}

extern "C" void kernel_launch(void* const* d_in, const int* in_sizes, int n_in,
                              void* d_out, int out_size, void* d_ws, size_t ws_size,
                              hipStream_t stream) {
    const float* W = (const float*)d_in[0];   // (4096, 4096)
    const float* K = (const float*)d_in[1];   // (512, 4096)
    const float* V = (const float*)d_in[2];   // (512, 4096)
    float* out = (float*)d_out;

    char* ws = (char*)d_ws;                    // 48 MB used
    bf16_t* Wt = (bf16_t*)(ws);                            // (4096,4096) W^T
    bf16_t* Kt = (bf16_t*)(ws + (size_t)32 * 1024 * 1024); // (4096,512) K^T
    bf16_t* Kb = (bf16_t*)(ws + (size_t)36 * 1024 * 1024); // (512,4096) K
    bf16_t* Vt = (bf16_t*)(ws + (size_t)40 * 1024 * 1024); // (4096,512) V^T
    bf16_t* Rt = (bf16_t*)(ws + (size_t)44 * 1024 * 1024); // (4096,512) R^T

    t_all      <<<dim3(64, 80), 256, 0, stream>>>(W, K, V, Wt, Kt, Kb, Vt);
    k1_residual<<<dim3(32, 8),  256, 0, stream>>>(Wt, Kb, Vt, Rt);
    k2_update  <<<dim3(32, 32), 256, 0, stream>>>(Kt, Rt, W, out);
}